// Round 11
// baseline (164.094 us; speedup 1.0000x reference)
//
#include <hip/hip_runtime.h>
#include <hip/hip_bf16.h>
#include <math.h>

typedef __bf16 bf16x8 __attribute__((ext_vector_type(8)));
typedef float  f32x4  __attribute__((ext_vector_type(4)));
typedef float  f32x16 __attribute__((ext_vector_type(16)));
typedef int    int2v  __attribute__((ext_vector_type(2)));
typedef unsigned int uint4v __attribute__((ext_vector_type(4)));
typedef unsigned short ushort_t;

#define LDK 72   // padded LDS row for preconvert transpose only

// ws layout (bytes):
//   Kg  : [12][4096][64] bf16  (gathered, per-head)          @ 0        (6291456)
//   VgT : [12][64][4096] bf16  (gathered, transposed)        @ 6291456  (6291456)
//   l_acc: [4096*12] f32                                     @ 12582912 (196608)
//   ctr : 8 per-XCD work-queue counters (int[8])             @ 12779520 (32)
#define KG_OFF  0
#define VGT_OFF 6291456
#define LACC_OFF 12582912
#define CTR_OFF  12779520

// ---------------- compile-time XCD-partitioned LPT item tables (chunk = 16) ----------------
// Item = (qt 128-row q-tile, head h, k-chunk c of <=16 tiles), enc = qt<<6|h<<2|c.
// Heads are statically assigned to 8 XCD bins (whole-head affinity: each bin's
// K/V working set ~1-2 MB, fits the XCD-private 4MB L2). Within each bin,
// items are cost-DESC sorted so per-bin dynamic claims realize LPT; exhausted
// bins steal from the ring (claims stay unique: one bin per item).
struct ItemTab { unsigned short v[896]; int beg[9]; };

constexpr ItemTab build_items(int causal) {
    ItemTab t{};
    for (int i = 0; i < 896; ++i) t.v[i] = 0xFFFF;
    const int head2bin[12] = {4, 5, 6, 7, 4, 5, 6, 7, 0, 1, 2, 3};
    int n = 0;
    for (int bin = 0; bin < 8; ++bin) {
        t.beg[bin] = n;
        for (int cost = 16; cost >= 1; --cost)
            for (int qt = 31; qt >= 0; --qt)
                for (int h = 11; h >= 0; --h) {
                    if (head2bin[h] != bin) continue;
                    const int group = h >> 2;
                    const int sl = 1024 << group;
                    const int qb = (qt << 7) & (sl - 1);
                    const int nkt = causal ? (((qb + 127) >> 6) + 1) : (sl >> 6);
                    for (int c = 0; c < 4; ++c) {
                        const int kt0 = c << 4;
                        if (kt0 >= nkt) continue;
                        const int rem = nkt - kt0;
                        const int cst = rem < 16 ? rem : 16;
                        if (cst == cost) t.v[n++] = (unsigned short)((qt << 6) | (h << 2) | c);
                    }
                }
    }
    t.beg[8] = n;
    return t;
}

__constant__ ItemTab g_tab_c = build_items(1);   // causal: 640 items
__constant__ ItemTab g_tab_n = build_items(0);   // non-causal: 896 items

__device__ __forceinline__ int gather_pos(int gi, int group) {
    const int lsl = 10 + group;           // log2(segment length)
    const int seg = gi >> lsl;
    const int j   = gi - (seg << lsl);
    return (seg << lsl) + group + ((j & 1023) << group);
}

// async 16B global->LDS (lane-linear LDS dest: base + lane*16)
__device__ __forceinline__ void gld_lds16(const ushort_t* g, __bf16* l) {
    __builtin_amdgcn_global_load_lds(
        (const __attribute__((address_space(1))) void*)g,
        (__attribute__((address_space(3))) void*)l, 16, 0, 0);
}

__device__ __forceinline__ unsigned int pk_bf16(float lo, float hi) {
    unsigned short a = __builtin_bit_cast(unsigned short, (__bf16)lo);
    unsigned short b = __builtin_bit_cast(unsigned short, (__bf16)hi);
    return ((unsigned int)b << 16) | (unsigned int)a;
}

__device__ __forceinline__ f32x16 zero16() {
    f32x16 z;
    #pragma unroll
    for (int i = 0; i < 16; ++i) z[i] = 0.f;
    return z;
}

// ---------------- pre-convert kernel (scatter-flip K; selective zero; 8 ctrs) ----------------
__global__ __launch_bounds__(256)
void preconvert_kernel(const float* __restrict__ K, const float* __restrict__ V,
                       ushort_t* __restrict__ Kg, ushort_t* __restrict__ VgT,
                       float* __restrict__ Out, float* __restrict__ l_acc,
                       int* __restrict__ ctr, const int* __restrict__ is_causal_p)
{
    const int HD = 768;
    int b = blockIdx.x;
    const int tid = threadIdx.x;
    if (b < 768) {
        if (b == 0 && tid < 8) ctr[tid] = 0;
        // zero Out, but only rows that get atomic accumulation (nkt>16 = multi-chunk)
        {
            const int causal = (*is_causal_p) != 0;
            const int rh = (b * 256 + tid) >> 2;          // 4 consecutive float4 = same rh
            const int h_ = rh % 12;
            const int row_ = rh / 12;
            const int ntf = 16 << (h_ >> 2);
            const int qt128 = row_ >> 7;
            const int qb_t = (qt128 << 1) & (ntf - 1);
            const int nkt = causal ? (qb_t + 2) : ntf;
            if (nkt > 16) {
                float4 z = {0.f, 0.f, 0.f, 0.f};
                float4* zp = (float4*)Out + ((size_t)b * 256 + tid) * 4;
                zp[0] = z; zp[1] = z; zp[2] = z; zp[3] = z;
            }
        }
        // K part (scatter-flip): read coalesced pos rows, write gi copies
        const int h = b % 12, p0 = (b / 12) * 64;
        const int group = h >> 2;
        const int pos = p0 + (tid >> 2);
        const int d0 = (tid & 3) << 4;
        const int lsl = 10 + group;
        const int rate = 1 << group;
        const int seg_base = (pos >> lsl) << lsl;
        const int po = pos - seg_base;
        const int rem = po - group;
        if (rem >= 0 && (rem & (rate - 1)) == 0) {
            const float* kp = K + (size_t)pos * HD + h * 64 + d0;
            float4 x0 = ((const float4*)kp)[0], x1 = ((const float4*)kp)[1];
            float4 x2 = ((const float4*)kp)[2], x3 = ((const float4*)kp)[3];
            bf16x8 w0, w1;
            w0[0]=(__bf16)x0.x; w0[1]=(__bf16)x0.y; w0[2]=(__bf16)x0.z; w0[3]=(__bf16)x0.w;
            w0[4]=(__bf16)x1.x; w0[5]=(__bf16)x1.y; w0[6]=(__bf16)x1.z; w0[7]=(__bf16)x1.w;
            w1[0]=(__bf16)x2.x; w1[1]=(__bf16)x2.y; w1[2]=(__bf16)x2.z; w1[3]=(__bf16)x2.w;
            w1[4]=(__bf16)x3.x; w1[5]=(__bf16)x3.y; w1[6]=(__bf16)x3.z; w1[7]=(__bf16)x3.w;
            const int jb = rem >> group;                     // 0..1023
            for (int k = 0; k < rate; ++k) {
                const int gi = seg_base + jb + (k << 10);
                ushort_t* out = Kg + ((size_t)(h * 4096 + gi)) * 64 + d0;
                *(bf16x8*)out = w0;
                *(bf16x8*)(out + 8) = w1;
            }
        }
    } else {
        // V part: VgT[h][d][gi] via LDS transpose (gathered reads)
        b -= 768;
        if (b < 192) l_acc[b * 256 + tid] = 0.f;   // zero l_acc: 49152 floats
        const int h = b % 12, gi0 = (b / 12) * 64;
        const int group = h >> 2;
        __shared__ __align__(16) __bf16 Ts[64 * LDK];
        const int gil = tid >> 2;
        const int d0 = (tid & 3) << 4;
        const int pos = gather_pos(gi0 + gil, group);
        const float* vp = V + (size_t)pos * HD + h * 64 + d0;
        float4 x0 = ((const float4*)vp)[0], x1 = ((const float4*)vp)[1];
        float4 x2 = ((const float4*)vp)[2], x3 = ((const float4*)vp)[3];
        bf16x8 w0, w1;
        w0[0]=(__bf16)x0.x; w0[1]=(__bf16)x0.y; w0[2]=(__bf16)x0.z; w0[3]=(__bf16)x0.w;
        w0[4]=(__bf16)x1.x; w0[5]=(__bf16)x1.y; w0[6]=(__bf16)x1.z; w0[7]=(__bf16)x1.w;
        w1[0]=(__bf16)x2.x; w1[1]=(__bf16)x2.y; w1[2]=(__bf16)x2.z; w1[3]=(__bf16)x2.w;
        w1[4]=(__bf16)x3.x; w1[5]=(__bf16)x3.y; w1[6]=(__bf16)x3.z; w1[7]=(__bf16)x3.w;
        *(bf16x8*)&Ts[gil * LDK + d0]     = w0;
        *(bf16x8*)&Ts[gil * LDK + d0 + 8] = w1;
        __syncthreads();
        const int d = tid >> 2, c = tid & 3;
        bf16x8 o0, o1;
        #pragma unroll
        for (int i = 0; i < 8; ++i) {
            o0[i] = Ts[(c * 16 + i) * LDK + d];
            o1[i] = Ts[(c * 16 + 8 + i) * LDK + d];
        }
        ushort_t* out = VgT + ((size_t)(h * 64 + d)) * 4096 + gi0 + c * 16;
        *(bf16x8*)out = o0;
        *(bf16x8*)(out + 8) = o1;
    }
}

// ---------------- main attention kernel ----------------
// R5-exact best-measured body (gld_lds staging, depth-2 double-buffer,
// 1-barrier counted pipeline, chunk-16) + XCD-AFFINITY claims: each block
// reads its hardware XCD id and pulls items from that XCD's head-partitioned
// bin (local-L2 reuse of K/V tiles), stealing round-robin when empty.
__global__ __launch_bounds__(256)
void dilated_attn_kernel(const float* __restrict__ Q,
                         const ushort_t* __restrict__ Kg,
                         const ushort_t* __restrict__ VgT,
                         const int* __restrict__ is_causal_p,
                         float* __restrict__ Out,
                         float* __restrict__ l_acc,
                         int* __restrict__ ctr)
{
    const int HD = 768;
    const int causal = (*is_causal_p) != 0;
    const ItemTab& tab = causal ? g_tab_c : g_tab_n;

    const int tid  = threadIdx.x;
    const int wave = tid >> 6;
    const int lane = tid & 63;
    const int l31  = lane & 31;
    const int hi   = lane >> 5;

    __shared__ __align__(16) __bf16 Ks[2][64 * 64];   // [key][d], swizzled
    __shared__ __align__(16) __bf16 Vs[2][64 * 64];   // [d][key], swizzled
    __shared__ int s_item;

    // hardware XCD id (m09). Wave-uniform; correctness does not depend on it
    // (any bin choice is valid), only L2 locality does.
    unsigned int xcc = 0;
    asm volatile("s_getreg_b32 %0, hwreg(HW_REG_XCC_ID)" : "=s"(xcc));
    const int myx = (int)(xcc & 7);

    // staging geometry (item-independent)
    const int bx16 = (((lane & 7) ^ (lane >> 3)) & 7) << 3;   // inverse-swizzled col (elems)
    const int r8   = lane >> 3;                               // 0..7

    for (int ring = 0; ring < 8; ++ring) {
        const int bin = (myx + ring) & 7;
        const int lo = tab.beg[bin], hicap = tab.beg[bin + 1];
        for (;;) {
            if (tid == 0) s_item = lo + atomicAdd(&ctr[bin], 1);
            __syncthreads();
            const int n = s_item;
            __syncthreads();          // all read s_item before tid0's next write
            if (n >= hicap) break;

            const int enc = tab.v[n];
            const int qt  = enc >> 6;
            const int h   = (enc >> 2) & 15;
            const int c   = enc & 3;
            const int group = h >> 2;
            const int sl    = 1024 << group;

            const int q0 = qt << 7;
            const int qb = q0 & (sl - 1);            // 128-aligned segment offset
            const int seg_start = q0 - qb;
            const int blk_diag = (qb + 127) >> 6;
            const int nkt = causal ? (blk_diag + 1) : (sl >> 6);
            const int kt0 = c << 4;
            const int kend = min(kt0 + 16, nkt);
            const int nch  = (nkt + 15) >> 4;

            const ushort_t* kg_head = Kg + (size_t)h * 4096 * 64;
            const ushort_t* vt_head = VgT + (size_t)h * 64 * 4096;

            auto stage = [&](int kt, int buf) {
                const ushort_t* kb = kg_head + ((size_t)(seg_start + (kt << 6)) << 6);
                const ushort_t* vb = vt_head + seg_start + (kt << 6);
                #pragma unroll
                for (int i = 0; i < 2; ++i) {
                    const int row = i * 32 + wave * 8 + r8;
                    gld_lds16(kb + row * 64 + bx16, &Ks[buf][(i * 32 + wave * 8) * 64]);
                    gld_lds16(vb + (size_t)row * 4096 + bx16, &Vs[buf][(i * 32 + wave * 8) * 64]);
                }
            };

            stage(kt0, 0);   // issue first tile before the (long-latency) Q loads

            // ---- Q fragments: lane (hi,l31) holds Q[q0+wave*32+l31][ds*16+hi*8 .. +8] ----
            const int qrow = q0 + wave * 32 + l31;
            const float* qptr = Q + (size_t)qrow * HD + h * 64;
            bf16x8 qf[4];
            {
                const float s = 0.125f * 1.4426950408889634f;
                #pragma unroll
                for (int ds = 0; ds < 4; ++ds) {
                    float4 x0 = ((const float4*)(qptr + ds * 16 + hi * 8))[0];
                    float4 x1 = ((const float4*)(qptr + ds * 16 + hi * 8))[1];
                    bf16x8 w;
                    w[0]=(__bf16)(x0.x*s); w[1]=(__bf16)(x0.y*s); w[2]=(__bf16)(x0.z*s); w[3]=(__bf16)(x0.w*s);
                    w[4]=(__bf16)(x1.x*s); w[5]=(__bf16)(x1.y*s); w[6]=(__bf16)(x1.z*s); w[7]=(__bf16)(x1.w*s);
                    qf[ds] = w;
                }
            }

            // per-wave diag tile; waves 0,1 -> qb/64; waves 2,3 -> qb/64+1
            const int mydiag = causal ? ((qb + wave * 32 + 31) >> 6) : 0x7fffffff;
            const int lrow   = ((wave & 1) << 5) + l31;   // local row within the diag tile

            f32x16 o0 = zero16(), o1 = zero16();          // O[q][d0..31], O[q][d32..63]
            float l_part = 0.f;

            for (int kt = kt0; kt < kend; ++kt) {
                const int cur = (kt - kt0) & 1;

                // stage(kt) issued one full tile ago -> latency hidden; no drain stall.
                asm volatile("s_waitcnt vmcnt(0)" ::: "memory");
                __builtin_amdgcn_s_barrier();             // all waves' stage(kt) landed
                __builtin_amdgcn_sched_barrier(0);        // no motion across the barrier

                // WAR-safe: everyone passed barrier => done reading buf cur^1
                if (kt + 1 < kend) stage(kt + 1, cur ^ 1);

                if (kt <= mydiag) {
                    // ---- S^T = K Q^T : col = q (lane-local), row = key ----
                    f32x16 s0 = zero16(), s1 = zero16();
                    const int xr = (l31 & 7);
                    __builtin_amdgcn_s_setprio(1);
                    #pragma unroll
                    for (int ds = 0; ds < 4; ++ds) {
                        const int cb = ds * 2 + hi;
                        bf16x8 k0 = *(const bf16x8*)&Ks[cur][l31 * 64        + ((cb ^ xr) << 3)];
                        bf16x8 k1 = *(const bf16x8*)&Ks[cur][(32 + l31) * 64 + ((cb ^ xr) << 3)];
                        s0 = __builtin_amdgcn_mfma_f32_32x32x16_bf16(k0, qf[ds], s0, 0, 0, 0);
                        s1 = __builtin_amdgcn_mfma_f32_32x32x16_bf16(k1, qf[ds], s1, 0, 0, 0);
                    }
                    __builtin_amdgcn_s_setprio(0);

                    // ---- P = 2^S, in-register, causal mask on the diag tile ----
                    float p[2][16];
                    const bool isdiag = causal && (kt == mydiag);
                    #pragma unroll
                    for (int r = 0; r < 16; ++r) {
                        float v0 = __builtin_amdgcn_exp2f(s0[r]);
                        float v1 = __builtin_amdgcn_exp2f(s1[r]);
                        if (isdiag) {
                            const int kl = (r & 3) + ((r >> 2) << 3) + (hi << 2);
                            if (kl > lrow)      v0 = 0.f;
                            if (kl + 32 > lrow) v1 = 0.f;
                        }
                        p[0][r] = v0; p[1][r] = v1;
                        l_part += v0 + v1;
                    }

                    // ---- pack bf16 + permlane32_swap -> PV A-frags; O += P V ----
                    __builtin_amdgcn_s_setprio(1);
                    #pragma unroll
                    for (int b = 0; b < 2; ++b) {           // key block: 0 -> keys 0-31, 1 -> 32-63
                        #pragma unroll
                        for (int ks2 = 0; ks2 < 2; ++ks2) { // k-slice within block (16 keys)
                            const int g = ks2 * 8;
                            int x0 = (int)pk_bf16(p[b][g + 0], p[b][g + 1]);
                            int x1 = (int)pk_bf16(p[b][g + 2], p[b][g + 3]);
                            int y0 = (int)pk_bf16(p[b][g + 4], p[b][g + 5]);
                            int y1 = (int)pk_bf16(p[b][g + 6], p[b][g + 7]);
                            int2v r02 = __builtin_amdgcn_permlane32_swap(x0, y0, false, false);
                            int2v r13 = __builtin_amdgcn_permlane32_swap(x1, y1, false, false);
                            uint4v t;
                            t[0] = (unsigned int)r02[0];
                            t[1] = (unsigned int)r13[0];
                            t[2] = (unsigned int)r02[1];
                            t[3] = (unsigned int)r13[1];
                            bf16x8 pa = __builtin_bit_cast(bf16x8, t);
                            const int kcb = (b * 2 + ks2) * 2 + hi;
                            bf16x8 v0 = *(const bf16x8*)&Vs[cur][l31 * 64        + ((kcb ^ xr) << 3)];
                            bf16x8 v1 = *(const bf16x8*)&Vs[cur][(32 + l31) * 64 + ((kcb ^ xr) << 3)];
                            o0 = __builtin_amdgcn_mfma_f32_32x32x16_bf16(pa, v0, o0, 0, 0, 0);
                            o1 = __builtin_amdgcn_mfma_f32_32x32x16_bf16(pa, v1, o1, 0, 0, 0);
                        }
                    }
                    __builtin_amdgcn_s_setprio(0);
                }
                // no end-of-iter barrier: next iter's top barrier provides ordering
            }

            // ---- epilogue: l lives per q-column (lane l31); O rows redistributed ----
            const float l2 = l_part + __shfl_xor(l_part, 32);   // full denom for q = qw + l31
            const int qw = q0 + wave * 32;
            if (nch == 1) {
                const float inv = 1.0f / l2;
                #pragma unroll
                for (int r = 0; r < 16; ++r) {
                    const int qloc = (r & 3) + ((r >> 2) << 3) + (hi << 2);
                    const float invq = __shfl(inv, qloc);       // lane qloc holds inv for q=qw+qloc
                    const int row = qw + qloc;
                    Out[(size_t)row * HD + h * 64 + l31]      = o0[r] * invq;
                    Out[(size_t)row * HD + h * 64 + 32 + l31] = o1[r] * invq;
                }
            } else {
                if (hi == 0) atomicAdd(&l_acc[(qw + l31) * 12 + h], l2);
                #pragma unroll
                for (int r = 0; r < 16; ++r) {
                    const int qloc = (r & 3) + ((r >> 2) << 3) + (hi << 2);
                    const int row = qw + qloc;
                    atomicAdd(&Out[(size_t)row * HD + h * 64 + l31],      o0[r]);
                    atomicAdd(&Out[(size_t)row * HD + h * 64 + 32 + l31], o1[r]);
                }
            }
        }
    }
}

// ---------------- finalize: divide multi-chunk rows by accumulated l ----------------
__global__ __launch_bounds__(256)
void finalize_kernel(float* __restrict__ Out, const float* __restrict__ l_acc,
                     const int* __restrict__ is_causal_p)
{
    const int causal = (*is_causal_p) != 0;
    const int idx = blockIdx.x * 256 + threadIdx.x;   // 0..786431 (float4 units)
    const int rh = idx >> 4;
    const int d4 = idx & 15;
    const int h = rh % 12;
    const int row = rh / 12;
    const int ntf = 16 << (h >> 2);                   // k-tiles per segment
    const int qt128 = row >> 7;
    const int qb_t = (qt128 << 1) & (ntf - 1);        // block qb in 64-tiles
    const int nkt = causal ? (qb_t + 2) : ntf;
    if (nkt <= 16) return;                            // single chunk: already normalized
    const float inv = 1.0f / l_acc[rh];
    float4* p = (float4*)Out + (size_t)rh * 16 + d4;
    float4 v = *p;
    v.x *= inv; v.y *= inv; v.z *= inv; v.w *= inv;
    *p = v;
}

extern "C" void kernel_launch(void* const* d_in, const int* in_sizes, int n_in,
                              void* d_out, int out_size, void* d_ws, size_t ws_size,
                              hipStream_t stream) {
    (void)in_sizes; (void)n_in; (void)out_size; (void)ws_size;
    const float* Q = (const float*)d_in[0];
    const float* K = (const float*)d_in[1];
    const float* V = (const float*)d_in[2];
    const int* isc = (const int*)d_in[3];
    float* Out = (float*)d_out;
    ushort_t* Kg   = (ushort_t*)((char*)d_ws + KG_OFF);
    ushort_t* VgT  = (ushort_t*)((char*)d_ws + VGT_OFF);
    float*    lacc = (float*)((char*)d_ws + LACC_OFF);
    int*      ctr  = (int*)((char*)d_ws + CTR_OFF);

    preconvert_kernel<<<1536, 256, 0, stream>>>(K, V, Kg, VgT, Out, lacc, ctr, isc);
    dilated_attn_kernel<<<512, 256, 0, stream>>>(Q, Kg, VgT, isc, Out, lacc, ctr);
    finalize_kernel<<<3072, 256, 0, stream>>>(Out, lacc, isc);
}

// Round 12
// 131.766 us; speedup vs baseline: 1.2453x; 1.2453x over previous
//
#include <hip/hip_runtime.h>
#include <hip/hip_bf16.h>
#include <math.h>

typedef __bf16 bf16x8 __attribute__((ext_vector_type(8)));
typedef float  f32x4  __attribute__((ext_vector_type(4)));
typedef float  f32x16 __attribute__((ext_vector_type(16)));
typedef int    int2v  __attribute__((ext_vector_type(2)));
typedef unsigned int uint4v __attribute__((ext_vector_type(4)));
typedef unsigned short ushort_t;

#define LDK 72   // padded LDS row for preconvert transpose only

// ws layout (bytes):
//   Kg  : [12][4096][64] bf16  (gathered, per-head)          @ 0        (6291456)
//   VgT : [12][64][4096] bf16  (gathered, transposed)        @ 6291456  (6291456)
//   l_acc: [4096*12] f32                                     @ 12582912 (196608)
//   ctr : work-queue counter (int)                           @ 12779520 (4)
#define KG_OFF  0
#define VGT_OFF 6291456
#define LACC_OFF 12582912
#define CTR_OFF  12779520

// ---------------- compile-time LPT item tables (chunk = 16, global queue) ----------------
// Item = (qt 128-row q-tile, head h, k-chunk c of <=16 tiles), enc = qt<<6|h<<2|c.
// Desc cost sort -> 512 claimant blocks realize LPT (R5 best-measured config).
struct ItemTab { unsigned short v[896]; int n; };

constexpr ItemTab build_items(int causal) {
    ItemTab t{};
    for (int i = 0; i < 896; ++i) t.v[i] = 0xFFFF;
    t.n = 0;
    for (int cost = 16; cost >= 1; --cost)
        for (int qt = 31; qt >= 0; --qt)
            for (int h = 11; h >= 0; --h) {
                const int group = h >> 2;
                const int sl = 1024 << group;
                const int qb = (qt << 7) & (sl - 1);
                const int nkt = causal ? (((qb + 127) >> 6) + 1) : (sl >> 6);
                for (int c = 0; c < 4; ++c) {
                    const int kt0 = c << 4;
                    if (kt0 >= nkt) continue;
                    const int rem = nkt - kt0;
                    const int cst = rem < 16 ? rem : 16;
                    if (cst == cost) t.v[t.n++] = (unsigned short)((qt << 6) | (h << 2) | c);
                }
            }
    return t;
}

__constant__ ItemTab g_tab_c = build_items(1);   // causal: 640 items
__constant__ ItemTab g_tab_n = build_items(0);   // non-causal: 896 items

__device__ __forceinline__ int gather_pos(int gi, int group) {
    const int lsl = 10 + group;           // log2(segment length)
    const int seg = gi >> lsl;
    const int j   = gi - (seg << lsl);
    return (seg << lsl) + group + ((j & 1023) << group);
}

// async 16B global->LDS (lane-linear LDS dest: base + lane*16)
__device__ __forceinline__ void gld_lds16(const ushort_t* g, __bf16* l) {
    __builtin_amdgcn_global_load_lds(
        (const __attribute__((address_space(1))) void*)g,
        (__attribute__((address_space(3))) void*)l, 16, 0, 0);
}

__device__ __forceinline__ unsigned int pk_bf16(float lo, float hi) {
    unsigned short a = __builtin_bit_cast(unsigned short, (__bf16)lo);
    unsigned short b = __builtin_bit_cast(unsigned short, (__bf16)hi);
    return ((unsigned int)b << 16) | (unsigned int)a;
}

__device__ __forceinline__ f32x16 zero16() {
    f32x16 z;
    #pragma unroll
    for (int i = 0; i < 16; ++i) z[i] = 0.f;
    return z;
}

// ---------------- pre-convert kernel (scatter-flip K; selective zero) ----------------
__global__ __launch_bounds__(256)
void preconvert_kernel(const float* __restrict__ K, const float* __restrict__ V,
                       ushort_t* __restrict__ Kg, ushort_t* __restrict__ VgT,
                       float* __restrict__ Out, float* __restrict__ l_acc,
                       int* __restrict__ ctr, const int* __restrict__ is_causal_p)
{
    const int HD = 768;
    int b = blockIdx.x;
    const int tid = threadIdx.x;
    if (b < 768) {
        if (b == 0 && tid == 0) *ctr = 0;
        // zero Out, but only rows that get atomic accumulation (nkt>16 = multi-chunk)
        {
            const int causal = (*is_causal_p) != 0;
            const int rh = (b * 256 + tid) >> 2;          // 4 consecutive float4 = same rh
            const int h_ = rh % 12;
            const int row_ = rh / 12;
            const int ntf = 16 << (h_ >> 2);
            const int qt128 = row_ >> 7;
            const int qb_t = (qt128 << 1) & (ntf - 1);
            const int nkt = causal ? (qb_t + 2) : ntf;
            if (nkt > 16) {
                float4 z = {0.f, 0.f, 0.f, 0.f};
                float4* zp = (float4*)Out + ((size_t)b * 256 + tid) * 4;
                zp[0] = z; zp[1] = z; zp[2] = z; zp[3] = z;
            }
        }
        // K part (scatter-flip): read coalesced pos rows, write gi copies
        const int h = b % 12, p0 = (b / 12) * 64;
        const int group = h >> 2;
        const int pos = p0 + (tid >> 2);
        const int d0 = (tid & 3) << 4;
        const int lsl = 10 + group;
        const int rate = 1 << group;
        const int seg_base = (pos >> lsl) << lsl;
        const int po = pos - seg_base;
        const int rem = po - group;
        if (rem >= 0 && (rem & (rate - 1)) == 0) {
            const float* kp = K + (size_t)pos * HD + h * 64 + d0;
            float4 x0 = ((const float4*)kp)[0], x1 = ((const float4*)kp)[1];
            float4 x2 = ((const float4*)kp)[2], x3 = ((const float4*)kp)[3];
            bf16x8 w0, w1;
            w0[0]=(__bf16)x0.x; w0[1]=(__bf16)x0.y; w0[2]=(__bf16)x0.z; w0[3]=(__bf16)x0.w;
            w0[4]=(__bf16)x1.x; w0[5]=(__bf16)x1.y; w0[6]=(__bf16)x1.z; w0[7]=(__bf16)x1.w;
            w1[0]=(__bf16)x2.x; w1[1]=(__bf16)x2.y; w1[2]=(__bf16)x2.z; w1[3]=(__bf16)x2.w;
            w1[4]=(__bf16)x3.x; w1[5]=(__bf16)x3.y; w1[6]=(__bf16)x3.z; w1[7]=(__bf16)x3.w;
            const int jb = rem >> group;                     // 0..1023
            for (int k = 0; k < rate; ++k) {
                const int gi = seg_base + jb + (k << 10);
                ushort_t* out = Kg + ((size_t)(h * 4096 + gi)) * 64 + d0;
                *(bf16x8*)out = w0;
                *(bf16x8*)(out + 8) = w1;
            }
        }
    } else {
        // V part: VgT[h][d][gi] via LDS transpose (gathered reads)
        b -= 768;
        if (b < 192) l_acc[b * 256 + tid] = 0.f;   // zero l_acc: 49152 floats
        const int h = b % 12, gi0 = (b / 12) * 64;
        const int group = h >> 2;
        __shared__ __align__(16) __bf16 Ts[64 * LDK];
        const int gil = tid >> 2;
        const int d0 = (tid & 3) << 4;
        const int pos = gather_pos(gi0 + gil, group);
        const float* vp = V + (size_t)pos * HD + h * 64 + d0;
        float4 x0 = ((const float4*)vp)[0], x1 = ((const float4*)vp)[1];
        float4 x2 = ((const float4*)vp)[2], x3 = ((const float4*)vp)[3];
        bf16x8 w0, w1;
        w0[0]=(__bf16)x0.x; w0[1]=(__bf16)x0.y; w0[2]=(__bf16)x0.z; w0[3]=(__bf16)x0.w;
        w0[4]=(__bf16)x1.x; w0[5]=(__bf16)x1.y; w0[6]=(__bf16)x1.z; w0[7]=(__bf16)x1.w;
        w1[0]=(__bf16)x2.x; w1[1]=(__bf16)x2.y; w1[2]=(__bf16)x2.z; w1[3]=(__bf16)x2.w;
        w1[4]=(__bf16)x3.x; w1[5]=(__bf16)x3.y; w1[6]=(__bf16)x3.z; w1[7]=(__bf16)x3.w;
        *(bf16x8*)&Ts[gil * LDK + d0]     = w0;
        *(bf16x8*)&Ts[gil * LDK + d0 + 8] = w1;
        __syncthreads();
        const int d = tid >> 2, c = tid & 3;
        bf16x8 o0, o1;
        #pragma unroll
        for (int i = 0; i < 8; ++i) {
            o0[i] = Ts[(c * 16 + i) * LDK + d];
            o1[i] = Ts[(c * 16 + 8 + i) * LDK + d];
        }
        ushort_t* out = VgT + ((size_t)(h * 64 + d)) * 4096 + gi0 + c * 16;
        *(bf16x8*)out = o0;
        *(bf16x8*)(out + 8) = o1;
    }
}

// ---------------- main attention kernel (R5-exact: best measured, 50.4 us) ----------------
// 512 persistent blocks pulling from the global LPT-sorted chunk-16 table.
// gld_lds staging, depth-2 LDS double-buffer, ONE barrier per k-tile with the
// counted-wait placed a full tile after issue. 128 q-rows/item, 4 waves x
// 32 q-rows, 32x32x16 MFMA, swapped QK^T, in-register softmax,
// permlane32_swap P-redistribution.
__global__ __launch_bounds__(256)
void dilated_attn_kernel(const float* __restrict__ Q,
                         const ushort_t* __restrict__ Kg,
                         const ushort_t* __restrict__ VgT,
                         const int* __restrict__ is_causal_p,
                         float* __restrict__ Out,
                         float* __restrict__ l_acc,
                         int* __restrict__ ctr)
{
    const int HD = 768;
    const int causal = (*is_causal_p) != 0;
    const ItemTab& tab = causal ? g_tab_c : g_tab_n;
    const int n_items = tab.n;

    const int tid  = threadIdx.x;
    const int wave = tid >> 6;
    const int lane = tid & 63;
    const int l31  = lane & 31;
    const int hi   = lane >> 5;

    __shared__ __align__(16) __bf16 Ks[2][64 * 64];   // [key][d], swizzled
    __shared__ __align__(16) __bf16 Vs[2][64 * 64];   // [d][key], swizzled
    __shared__ int s_item;

    // staging geometry (item-independent)
    const int bx16 = (((lane & 7) ^ (lane >> 3)) & 7) << 3;   // inverse-swizzled col (elems)
    const int r8   = lane >> 3;                               // 0..7

    for (;;) {
        if (tid == 0) s_item = atomicAdd(ctr, 1);
        __syncthreads();
        const int n = s_item;
        __syncthreads();          // all read s_item before tid0's next write
        if (n >= n_items) break;

        const int enc = tab.v[n];
        const int qt  = enc >> 6;
        const int h   = (enc >> 2) & 15;
        const int c   = enc & 3;
        const int group = h >> 2;
        const int sl    = 1024 << group;

        const int q0 = qt << 7;
        const int qb = q0 & (sl - 1);            // 128-aligned segment offset
        const int seg_start = q0 - qb;
        const int blk_diag = (qb + 127) >> 6;
        const int nkt = causal ? (blk_diag + 1) : (sl >> 6);
        const int kt0 = c << 4;
        const int kend = min(kt0 + 16, nkt);
        const int nch  = (nkt + 15) >> 4;

        const ushort_t* kg_head = Kg + (size_t)h * 4096 * 64;
        const ushort_t* vt_head = VgT + (size_t)h * 64 * 4096;

        auto stage = [&](int kt, int buf) {
            const ushort_t* kb = kg_head + ((size_t)(seg_start + (kt << 6)) << 6);
            const ushort_t* vb = vt_head + seg_start + (kt << 6);
            #pragma unroll
            for (int i = 0; i < 2; ++i) {
                const int row = i * 32 + wave * 8 + r8;
                gld_lds16(kb + row * 64 + bx16, &Ks[buf][(i * 32 + wave * 8) * 64]);
                gld_lds16(vb + (size_t)row * 4096 + bx16, &Vs[buf][(i * 32 + wave * 8) * 64]);
            }
        };

        stage(kt0, 0);   // issue first tile before the (long-latency) Q loads

        // ---- Q fragments: lane (hi,l31) holds Q[q0+wave*32+l31][ds*16+hi*8 .. +8] ----
        const int qrow = q0 + wave * 32 + l31;
        const float* qptr = Q + (size_t)qrow * HD + h * 64;
        bf16x8 qf[4];
        {
            const float s = 0.125f * 1.4426950408889634f;
            #pragma unroll
            for (int ds = 0; ds < 4; ++ds) {
                float4 x0 = ((const float4*)(qptr + ds * 16 + hi * 8))[0];
                float4 x1 = ((const float4*)(qptr + ds * 16 + hi * 8))[1];
                bf16x8 w;
                w[0]=(__bf16)(x0.x*s); w[1]=(__bf16)(x0.y*s); w[2]=(__bf16)(x0.z*s); w[3]=(__bf16)(x0.w*s);
                w[4]=(__bf16)(x1.x*s); w[5]=(__bf16)(x1.y*s); w[6]=(__bf16)(x1.z*s); w[7]=(__bf16)(x1.w*s);
                qf[ds] = w;
            }
        }

        // per-wave diag tile; waves 0,1 -> qb/64; waves 2,3 -> qb/64+1
        const int mydiag = causal ? ((qb + wave * 32 + 31) >> 6) : 0x7fffffff;
        const int lrow   = ((wave & 1) << 5) + l31;   // local row within the diag tile

        f32x16 o0 = zero16(), o1 = zero16();          // O[q][d0..31], O[q][d32..63]
        float l_part = 0.f;

        for (int kt = kt0; kt < kend; ++kt) {
            const int cur = (kt - kt0) & 1;

            // stage(kt) issued one full tile ago -> latency hidden; no drain stall.
            asm volatile("s_waitcnt vmcnt(0)" ::: "memory");
            __builtin_amdgcn_s_barrier();             // all waves' stage(kt) landed
            __builtin_amdgcn_sched_barrier(0);        // no motion across the barrier

            // WAR-safe: everyone passed barrier => done reading buf cur^1
            if (kt + 1 < kend) stage(kt + 1, cur ^ 1);

            if (kt <= mydiag) {
                // ---- S^T = K Q^T : col = q (lane-local), row = key ----
                f32x16 s0 = zero16(), s1 = zero16();
                const int xr = (l31 & 7);
                __builtin_amdgcn_s_setprio(1);
                #pragma unroll
                for (int ds = 0; ds < 4; ++ds) {
                    const int cb = ds * 2 + hi;
                    bf16x8 k0 = *(const bf16x8*)&Ks[cur][l31 * 64        + ((cb ^ xr) << 3)];
                    bf16x8 k1 = *(const bf16x8*)&Ks[cur][(32 + l31) * 64 + ((cb ^ xr) << 3)];
                    s0 = __builtin_amdgcn_mfma_f32_32x32x16_bf16(k0, qf[ds], s0, 0, 0, 0);
                    s1 = __builtin_amdgcn_mfma_f32_32x32x16_bf16(k1, qf[ds], s1, 0, 0, 0);
                }
                __builtin_amdgcn_s_setprio(0);

                // ---- P = 2^S, in-register, causal mask on the diag tile ----
                float p[2][16];
                const bool isdiag = causal && (kt == mydiag);
                #pragma unroll
                for (int r = 0; r < 16; ++r) {
                    float v0 = __builtin_amdgcn_exp2f(s0[r]);
                    float v1 = __builtin_amdgcn_exp2f(s1[r]);
                    if (isdiag) {
                        const int kl = (r & 3) + ((r >> 2) << 3) + (hi << 2);
                        if (kl > lrow)      v0 = 0.f;
                        if (kl + 32 > lrow) v1 = 0.f;
                    }
                    p[0][r] = v0; p[1][r] = v1;
                    l_part += v0 + v1;
                }

                // ---- pack bf16 + permlane32_swap -> PV A-frags; O += P V ----
                __builtin_amdgcn_s_setprio(1);
                #pragma unroll
                for (int b = 0; b < 2; ++b) {           // key block: 0 -> keys 0-31, 1 -> 32-63
                    #pragma unroll
                    for (int ks2 = 0; ks2 < 2; ++ks2) { // k-slice within block (16 keys)
                        const int g = ks2 * 8;
                        int x0 = (int)pk_bf16(p[b][g + 0], p[b][g + 1]);
                        int x1 = (int)pk_bf16(p[b][g + 2], p[b][g + 3]);
                        int y0 = (int)pk_bf16(p[b][g + 4], p[b][g + 5]);
                        int y1 = (int)pk_bf16(p[b][g + 6], p[b][g + 7]);
                        int2v r02 = __builtin_amdgcn_permlane32_swap(x0, y0, false, false);
                        int2v r13 = __builtin_amdgcn_permlane32_swap(x1, y1, false, false);
                        uint4v t;
                        t[0] = (unsigned int)r02[0];
                        t[1] = (unsigned int)r13[0];
                        t[2] = (unsigned int)r02[1];
                        t[3] = (unsigned int)r13[1];
                        bf16x8 pa = __builtin_bit_cast(bf16x8, t);
                        const int kcb = (b * 2 + ks2) * 2 + hi;
                        bf16x8 v0 = *(const bf16x8*)&Vs[cur][l31 * 64        + ((kcb ^ xr) << 3)];
                        bf16x8 v1 = *(const bf16x8*)&Vs[cur][(32 + l31) * 64 + ((kcb ^ xr) << 3)];
                        o0 = __builtin_amdgcn_mfma_f32_32x32x16_bf16(pa, v0, o0, 0, 0, 0);
                        o1 = __builtin_amdgcn_mfma_f32_32x32x16_bf16(pa, v1, o1, 0, 0, 0);
                    }
                }
                __builtin_amdgcn_s_setprio(0);
            }
            // no end-of-iter barrier: next iter's top barrier provides ordering
        }

        // ---- epilogue: l lives per q-column (lane l31); O rows redistributed ----
        const float l2 = l_part + __shfl_xor(l_part, 32);   // full denom for q = qw + l31
        const int qw = q0 + wave * 32;
        if (nch == 1) {
            const float inv = 1.0f / l2;
            #pragma unroll
            for (int r = 0; r < 16; ++r) {
                const int qloc = (r & 3) + ((r >> 2) << 3) + (hi << 2);
                const float invq = __shfl(inv, qloc);       // lane qloc holds inv for q=qw+qloc
                const int row = qw + qloc;
                Out[(size_t)row * HD + h * 64 + l31]      = o0[r] * invq;
                Out[(size_t)row * HD + h * 64 + 32 + l31] = o1[r] * invq;
            }
        } else {
            if (hi == 0) atomicAdd(&l_acc[(qw + l31) * 12 + h], l2);
            #pragma unroll
            for (int r = 0; r < 16; ++r) {
                const int qloc = (r & 3) + ((r >> 2) << 3) + (hi << 2);
                const int row = qw + qloc;
                atomicAdd(&Out[(size_t)row * HD + h * 64 + l31],      o0[r]);
                atomicAdd(&Out[(size_t)row * HD + h * 64 + 32 + l31], o1[r]);
            }
        }
    }
}

// ---------------- finalize: divide multi-chunk rows by accumulated l ----------------
__global__ __launch_bounds__(256)
void finalize_kernel(float* __restrict__ Out, const float* __restrict__ l_acc,
                     const int* __restrict__ is_causal_p)
{
    const int causal = (*is_causal_p) != 0;
    const int idx = blockIdx.x * 256 + threadIdx.x;   // 0..786431 (float4 units)
    const int rh = idx >> 4;
    const int d4 = idx & 15;
    const int h = rh % 12;
    const int row = rh / 12;
    const int ntf = 16 << (h >> 2);                   // k-tiles per segment
    const int qt128 = row >> 7;
    const int qb_t = (qt128 << 1) & (ntf - 1);        // block qb in 64-tiles
    const int nkt = causal ? (qb_t + 2) : ntf;
    if (nkt <= 16) return;                            // single chunk: already normalized
    const float inv = 1.0f / l_acc[rh];
    float4* p = (float4*)Out + (size_t)rh * 16 + d4;
    float4 v = *p;
    v.x *= inv; v.y *= inv; v.z *= inv; v.w *= inv;
    *p = v;
}

extern "C" void kernel_launch(void* const* d_in, const int* in_sizes, int n_in,
                              void* d_out, int out_size, void* d_ws, size_t ws_size,
                              hipStream_t stream) {
    (void)in_sizes; (void)n_in; (void)out_size; (void)ws_size;
    const float* Q = (const float*)d_in[0];
    const float* K = (const float*)d_in[1];
    const float* V = (const float*)d_in[2];
    const int* isc = (const int*)d_in[3];
    float* Out = (float*)d_out;
    ushort_t* Kg   = (ushort_t*)((char*)d_ws + KG_OFF);
    ushort_t* VgT  = (ushort_t*)((char*)d_ws + VGT_OFF);
    float*    lacc = (float*)((char*)d_ws + LACC_OFF);
    int*      ctr  = (int*)((char*)d_ws + CTR_OFF);

    preconvert_kernel<<<1536, 256, 0, stream>>>(K, V, Kg, VgT, Out, lacc, ctr, isc);
    dilated_attn_kernel<<<512, 256, 0, stream>>>(Q, Kg, VgT, isc, Out, lacc, ctr);
    finalize_kernel<<<3072, 256, 0, stream>>>(Out, lacc, isc);
}